// Round 7
// baseline (1127.949 us; speedup 1.0000x reference)
//
#include <hip/hip_runtime.h>

#define HF 128

typedef __attribute__((ext_vector_type(8))) short short8;
typedef __attribute__((ext_vector_type(16))) float f32x16;

__device__ inline unsigned short f2bf(float x) {
  unsigned u = __float_as_uint(x);
  unsigned r = u + 0x7fffu + ((u >> 16) & 1u);
  return (unsigned short)(r >> 16);
}

// split 8 fp32 -> bf16 hi (truncate) + bf16 lo (residual, RNE)
__device__ inline void split8(const float4 fa, const float4 fb, short8& hi, short8& lo)
{
  float f[8] = {fa.x, fa.y, fa.z, fa.w, fb.x, fb.y, fb.z, fb.w};
  union { unsigned int u[4]; short8 s; } H, L;
#pragma unroll
  for (int p = 0; p < 4; ++p) {
    unsigned u0 = __float_as_uint(f[2 * p]);
    unsigned u1 = __float_as_uint(f[2 * p + 1]);
    H.u[p] = (u0 >> 16) | (u1 & 0xffff0000u);
    float l0 = f[2 * p]     - __uint_as_float(u0 & 0xffff0000u);
    float l1 = f[2 * p + 1] - __uint_as_float(u1 & 0xffff0000u);
    L.u[p] = (unsigned)f2bf(l0) | ((unsigned)f2bf(l1) << 16);
  }
  hi = H.s; lo = L.s;
}

// ---------- input projection: out[N][128] = x[N][K] @ w[K][128] + b ----------
template<int K>
__global__ __launch_bounds__(256) void proj_kernel(
    const float* __restrict__ x, const float* __restrict__ w,
    const float* __restrict__ b, float* __restrict__ out, int N)
{
  __shared__ float w_s[K][HF];
  __shared__ float x_s[64][K];
  const int tid = threadIdx.x;
  const int r0 = blockIdx.x * 64;

  for (int idx = tid; idx < K * (HF / 4); idx += 256) {
    int k = idx >> 5, c4 = idx & 31;
    *(float4*)&w_s[k][c4 * 4] = *(const float4*)(w + (size_t)k * HF + c4 * 4);
  }
  for (int idx = tid; idx < 64 * (K / 4); idx += 256) {
    int r = idx / (K / 4), c4 = idx % (K / 4);
    int row = r0 + r;
    float4 v = {0.f, 0.f, 0.f, 0.f};
    if (row < N) v = *(const float4*)(x + (size_t)row * K + c4 * 4);
    *(float4*)&x_s[r][c4 * 4] = v;
  }
  __syncthreads();

  const int cg = tid & 31;
  const int rg = tid >> 5;
  const int jc = cg * 4;
  const float4 bv = *(const float4*)(b + jc);
  float acc[8][4];
#pragma unroll
  for (int rr = 0; rr < 8; ++rr) {
    acc[rr][0] = bv.x; acc[rr][1] = bv.y; acc[rr][2] = bv.z; acc[rr][3] = bv.w;
  }

  for (int k = 0; k < K; k += 4) {
    float4 wv[4];
#pragma unroll
    for (int t = 0; t < 4; ++t) wv[t] = *(const float4*)&w_s[k + t][jc];
#pragma unroll
    for (int rr = 0; rr < 8; ++rr) {
      const float4 x4 = *(const float4*)&x_s[rg * 8 + rr][k];
      float xa[4] = {x4.x, x4.y, x4.z, x4.w};
#pragma unroll
      for (int t = 0; t < 4; ++t) {
        acc[rr][0] = fmaf(xa[t], wv[t].x, acc[rr][0]);
        acc[rr][1] = fmaf(xa[t], wv[t].y, acc[rr][1]);
        acc[rr][2] = fmaf(xa[t], wv[t].z, acc[rr][2]);
        acc[rr][3] = fmaf(xa[t], wv[t].w, acc[rr][3]);
      }
    }
  }

#pragma unroll
  for (int rr = 0; rr < 8; ++rr) {
    int row = r0 + rg * 8 + rr;
    if (row < N) {
      float4 o = {acc[rr][0], acc[rr][1], acc[rr][2], acc[rr][3]};
      *(float4*)(out + (size_t)row * HF + jc) = o;
    }
  }
}

// ---------- CSR build ----------
__global__ void count_kernel(const int* __restrict__ dst, int* __restrict__ cnt,
                             int* __restrict__ pos, int E)
{
  int e = blockIdx.x * blockDim.x + threadIdx.x;
  if (e < E) pos[e] = atomicAdd(&cnt[dst[e]], 1);
}

__global__ __launch_bounds__(1024) void scan_p1(int* __restrict__ data, int* __restrict__ bsum, int n)
{
  __shared__ int s[1024];
  int tid = threadIdx.x;
  int i = blockIdx.x * 1024 + tid;
  int v = (i < n) ? data[i] : 0;
  s[tid] = v;
  __syncthreads();
  for (int off = 1; off < 1024; off <<= 1) {
    int t = (tid >= off) ? s[tid - off] : 0;
    __syncthreads();
    s[tid] += t;
    __syncthreads();
  }
  if (i < n) data[i] = s[tid] - v;
  if (tid == 1023) bsum[blockIdx.x] = s[1023];
}

__global__ __launch_bounds__(1024) void scan_p2(int* __restrict__ bsum, int nb)
{
  __shared__ int s[1024];
  int tid = threadIdx.x;
  int v = (tid < nb) ? bsum[tid] : 0;
  s[tid] = v;
  __syncthreads();
  for (int off = 1; off < 1024; off <<= 1) {
    int t = (tid >= off) ? s[tid - off] : 0;
    __syncthreads();
    s[tid] += t;
    __syncthreads();
  }
  if (tid < nb) bsum[tid] = s[tid] - v;
}

__global__ __launch_bounds__(1024) void scan_p3(int* __restrict__ data, const int* __restrict__ bsum,
                                                int n, int total)
{
  int i = blockIdx.x * 1024 + threadIdx.x;
  if (i < n) data[i] += bsum[blockIdx.x];
  if (i == 0) data[n] = total;
}

__global__ void fill_kernel(const int* __restrict__ dst, const int* __restrict__ src,
                            const int* __restrict__ rp, const int* __restrict__ pos,
                            int* __restrict__ colv, int E)
{
  int e = blockIdx.x * blockDim.x + threadIdx.x;
  if (e < E) colv[rp[dst[e]] + pos[e]] = src[e];
}

// ---------- mean aggregation (v2, measured-best): one wave per dst ------------
// lanes 0-31 take even edge slots, 32-63 odd; each lane reads float2 of the row.
__global__ __launch_bounds__(256) void agg_kernel(
    const float* __restrict__ feat, const int* __restrict__ rp,
    const int* __restrict__ colv, float* __restrict__ out, int ndst)
{
  int gw = (int)((blockIdx.x * blockDim.x + threadIdx.x) >> 6);
  int lane = threadIdx.x & 63;
  int half = lane >> 5;
  int fi = (lane & 31) * 4;
  int nw = (int)((gridDim.x * blockDim.x) >> 6);
  for (int d = gw; d < ndst; d += nw) {
    int beg = rp[d], end = rp[d + 1];
    float4 a0 = {0.f, 0.f, 0.f, 0.f}, a1 = {0.f, 0.f, 0.f, 0.f};
    int j = beg + half;
    for (; j + 2 < end; j += 4) {
      int s0 = colv[j];
      int s1 = colv[j + 2];
      const float4 v0 = *(const float4*)(feat + (size_t)s0 * HF + fi);
      const float4 v1 = *(const float4*)(feat + (size_t)s1 * HF + fi);
      a0.x += v0.x; a0.y += v0.y; a0.z += v0.z; a0.w += v0.w;
      a1.x += v1.x; a1.y += v1.y; a1.z += v1.z; a1.w += v1.w;
    }
    for (; j < end; j += 2) {
      int s0 = colv[j];
      const float4 v0 = *(const float4*)(feat + (size_t)s0 * HF + fi);
      a0.x += v0.x; a0.y += v0.y; a0.z += v0.z; a0.w += v0.w;
    }
    float4 a;
    a.x = a0.x + a1.x; a.y = a0.y + a1.y; a.z = a0.z + a1.z; a.w = a0.w + a1.w;
    a.x += __shfl_xor(a.x, 32);
    a.y += __shfl_xor(a.y, 32);
    a.z += __shfl_xor(a.z, 32);
    a.w += __shfl_xor(a.w, 32);
    if (half == 0) {
      int dg = end - beg;
      float inv = 1.0f / (float)(dg > 0 ? dg : 1);
      float4 o = {a.x * inv, a.y * inv, a.z * inv, a.w * inv};
      *(float4*)(out + (size_t)d * HF + fi) = o;
    }
  }
}

// ---------- weight pack: W=[Wl;Wr] (256x128) -> bf16 hi/lo MFMA-frag tiles ----
// layout: bpack + combo*131072 + kc*16384 + part*8192 + kt*4096 + ct*1024 + lane*16
// frag (32x32x16 B operand): lane l: col = ct*32 + (l&31), k = kc*32+kt*16+(l>>5)*8+j
__global__ void wpack_kernel(const float* __restrict__ wl, const float* __restrict__ wr,
                             unsigned char* __restrict__ bpack, int ncombo)
{
  int t = blockIdx.x * 256 + threadIdx.x;
  int total = ncombo << 12;
  if (t >= total) return;
  int lane = t & 63;
  int ct = (t >> 6) & 3;
  int kt = (t >> 8) & 1;
  int kc = (t >> 9) & 7;
  int combo = t >> 12;
  const float* WL = wl + (size_t)combo * HF * HF;
  const float* WR = wr + (size_t)combo * HF * HF;
  int col = ct * 32 + (lane & 31);
  int kbase = kc * 32 + kt * 16 + (lane >> 5) * 8;
  float f[8];
#pragma unroll
  for (int j = 0; j < 8; ++j) {
    int k = kbase + j;
    f[j] = (k < HF) ? WL[(size_t)k * HF + col] : WR[(size_t)(k - HF) * HF + col];
  }
  unsigned int hi[4], lo[4];
#pragma unroll
  for (int p = 0; p < 4; ++p) {
    unsigned u0 = __float_as_uint(f[2 * p]);
    unsigned u1 = __float_as_uint(f[2 * p + 1]);
    hi[p] = (u0 >> 16) | (u1 & 0xffff0000u);
    float l0 = f[2 * p]     - __uint_as_float(u0 & 0xffff0000u);
    float l1 = f[2 * p + 1] - __uint_as_float(u1 & 0xffff0000u);
    lo[p] = (unsigned)f2bf(l0) | ((unsigned)f2bf(l1) << 16);
  }
  size_t base = (size_t)combo * 131072 + kc * 16384 + kt * 4096 + ct * 1024 + lane * 16;
  uint4 h = {hi[0], hi[1], hi[2], hi[3]};
  uint4 l = {lo[0], lo[1], lo[2], lo[3]};
  *(uint4*)(bpack + base) = h;
  *(uint4*)(bpack + base + 8192) = l;
}

// ---------- fused SAGE layer v5: barrier-free, all-register -------------------
// out = relu([agg|x] @ [Wl;Wr] + b). block 256 = 4 waves; tile 64 rows x 128
// cols; each wave privately owns 32 rows x 64 cols (2x 32x32 acc tiles).
// NO LDS, NO barriers: lane loads its own A fragment straight from global
// (lanes l and l+32 cover the same 64B line halves -> full line utilization;
// each row fetched exactly once). B frags stream from the L2-resident pack.
// The fully-unrolled chunk loop is free for the compiler to software-pipeline.
union BU { uint4 u; short8 s; };

__global__ __launch_bounds__(256) void sage_mfma(
    const float* __restrict__ agg, const float* __restrict__ x,
    const unsigned char* __restrict__ bpk, const float* __restrict__ bias,
    float* __restrict__ out, int N)
{
  const int tid = threadIdx.x;
  const int lane = tid & 63;
  const int w = tid >> 6;
  const int wrow = w >> 1;               // 0..1 -> rows +wrow*32
  const int wcol = w & 1;                // 0..1 -> cols +wcol*64
  const int rbase = blockIdx.x * 64 + wrow * 32;
  const int row = rbase + (lane & 31);
  const bool rok = row < N;
  const int khalf = (lane >> 5) * 8;     // 0 or 8 (k within 16-slice)

  f32x16 acc[2];
#pragma unroll
  for (int c = 0; c < 2; ++c)
#pragma unroll
    for (int i = 0; i < 16; ++i) acc[c][i] = 0.f;

#pragma unroll
  for (int kc = 0; kc < 8; ++kc) {
    const float* srcp = (kc < 4) ? agg : x;
    const int cb = (kc & 3) * 32;

    // A fragments: 2 kt-slices, direct global loads
    short8 ahi[2], alo[2];
#pragma unroll
    for (int kt = 0; kt < 2; ++kt) {
      float4 fa = {0.f, 0.f, 0.f, 0.f}, fb = {0.f, 0.f, 0.f, 0.f};
      if (rok) {
        const float* p = srcp + (size_t)row * HF + cb + kt * 16 + khalf;
        fa = *(const float4*)p;
        fb = *(const float4*)(p + 4);
      }
      split8(fa, fb, ahi[kt], alo[kt]);
    }

    // B fragments: direct global->reg from packed weights (L2-resident)
    const uint4* gb = (const uint4*)(bpk + (size_t)kc * 16384);
    BU bhi[2][2], blo[2][2];               // [kt][ct]
#pragma unroll
    for (int kt = 0; kt < 2; ++kt)
#pragma unroll
      for (int ct = 0; ct < 2; ++ct) {
        int fi = kt * 256 + (wcol * 2 + ct) * 64 + lane;
        bhi[kt][ct].u = gb[fi];
        blo[kt][ct].u = gb[512 + fi];
      }

#pragma unroll
    for (int kt = 0; kt < 2; ++kt)
#pragma unroll
      for (int ct = 0; ct < 2; ++ct) {
        acc[ct] = __builtin_amdgcn_mfma_f32_32x32x16_bf16(ahi[kt], bhi[kt][ct].s, acc[ct], 0, 0, 0);
        acc[ct] = __builtin_amdgcn_mfma_f32_32x32x16_bf16(ahi[kt], blo[kt][ct].s, acc[ct], 0, 0, 0);
        acc[ct] = __builtin_amdgcn_mfma_f32_32x32x16_bf16(alo[kt], bhi[kt][ct].s, acc[ct], 0, 0, 0);
      }
  }

  // epilogue: bias + relu. C/D layout: col=lane&31, row=(reg&3)+8*(reg>>2)+4*(lane>>5)
#pragma unroll
  for (int ct = 0; ct < 2; ++ct) {
    int gcol = wcol * 64 + ct * 32 + (lane & 31);
    float bv = bias[gcol];
#pragma unroll
    for (int reg = 0; reg < 16; ++reg) {
      int row_l = (reg & 3) + 8 * (reg >> 2) + 4 * (lane >> 5);
      int grow = rbase + row_l;
      if (grow < N) {
        float v = acc[ct][reg] + bv;
        out[(size_t)grow * HF + gcol] = fmaxf(v, 0.f);
      }
    }
  }
}

extern "C" void kernel_launch(void* const* d_in, const int* in_sizes, int n_in,
                              void* d_out, int out_size, void* d_ws, size_t ws_size,
                              hipStream_t stream)
{
  const float* x_user  = (const float*)d_in[0];
  const float* x_item  = (const float*)d_in[1];
  const float* user_w  = (const float*)d_in[2];
  const float* user_b  = (const float*)d_in[3];
  const float* item_w  = (const float*)d_in[4];
  const float* item_b  = (const float*)d_in[5];
  const float* conv_wl = (const float*)d_in[6];
  const float* conv_bl = (const float*)d_in[7];
  const float* conv_wr = (const float*)d_in[8];
  const int* src_u2i = (const int*)d_in[9];
  const int* dst_u2i = (const int*)d_in[10];
  const int* src_i2u = (const int*)d_in[11];
  const int* dst_i2u = (const int*)d_in[12];

  const int NU = in_sizes[0] / 32;
  const int NI = in_sizes[1] / 64;
  const int E  = in_sizes[9];
  const int L  = in_sizes[6] / (2 * HF * HF);

  float* out_u = (float*)d_out;
  float* out_i = out_u + (size_t)NU * HF;

  char* wsb = (char*)d_ws;
  size_t off = 0;
  auto alloc = [&](size_t bytes) -> void* {
    void* p = wsb + off;
    off = (off + bytes + 255) & ~(size_t)255;
    return p;
  };
  float* uA    = (float*)alloc((size_t)NU * HF * 4);
  float* iA    = (float*)alloc((size_t)NI * HF * 4);
  float* agg_u = (float*)alloc((size_t)NU * HF * 4);
  float* agg_i = (float*)alloc((size_t)NI * HF * 4);
  int* rp_i    = (int*)alloc((size_t)(NI + 1) * 4);
  int* rp_u    = (int*)alloc((size_t)(NU + 1) * 4);
  int* pos     = (int*)alloc((size_t)E * 4);
  int* col_u2i = (int*)alloc((size_t)E * 4);
  int* col_i2u = (int*)alloc((size_t)E * 4);
  int* bsum    = (int*)alloc(4096 * 4);
  unsigned char* bpack = (unsigned char*)alloc((size_t)(2 * L) * 131072);
  (void)ws_size; (void)n_in; (void)out_size;

  // 1) input projections (into d_out, consumed by layer 0)
  proj_kernel<32><<<(NU + 63) / 64, 256, 0, stream>>>(x_user, user_w, user_b, out_u, NU);
  proj_kernel<64><<<(NI + 63) / 64, 256, 0, stream>>>(x_item, item_w, item_b, out_i, NI);

  // 2) weight packing (once; 2L combos)
  {
    int total = (2 * L) << 12;
    wpack_kernel<<<(total + 255) / 256, 256, 0, stream>>>(conv_wl, conv_wr, bpack, 2 * L);
  }

  // 3) CSR build for both directions (graph reused across layers)
  auto build_csr = [&](const int* dst, const int* srcv, int* rp, int* colv, int n) {
    (void)hipMemsetAsync(rp, 0, (size_t)(n + 1) * sizeof(int), stream);
    int gE = (E + 255) / 256;
    count_kernel<<<gE, 256, 0, stream>>>(dst, rp, pos, E);
    int nb = (n + 1023) / 1024;
    scan_p1<<<nb, 1024, 0, stream>>>(rp, bsum, n);
    scan_p2<<<1, 1024, 0, stream>>>(bsum, nb);
    scan_p3<<<nb, 1024, 0, stream>>>(rp, bsum, n, E);
    fill_kernel<<<gE, 256, 0, stream>>>(dst, srcv, rp, pos, colv, E);
  };
  build_csr(dst_u2i, src_u2i, rp_i, col_u2i, NI);
  build_csr(dst_i2u, src_i2u, rp_u, col_i2u, NU);

  // 4) layers
  const float* cu = out_u;
  const float* ci = out_i;
  for (int l = 0; l < L; ++l) {
    float* nu = (l & 1) ? out_u : uA;
    float* ni = (l & 1) ? out_i : iA;

    agg_kernel<<<(NI + 3) / 4, 256, 0, stream>>>(cu, rp_i, col_u2i, agg_i, NI);
    agg_kernel<<<(NU + 3) / 4, 256, 0, stream>>>(ci, rp_u, col_i2u, agg_u, NU);

    const unsigned char* bp0 = bpack + (size_t)(l * 2 + 0) * 131072;
    const unsigned char* bp1 = bpack + (size_t)(l * 2 + 1) * 131072;
    const float* bl0 = conv_bl + (size_t)(l * 2 + 0) * HF;
    const float* bl1 = conv_bl + (size_t)(l * 2 + 1) * HF;

    sage_mfma<<<(NI + 63) / 64, 256, 0, stream>>>(agg_i, ci, bp0, bl0, ni, NI);
    sage_mfma<<<(NU + 63) / 64, 256, 0, stream>>>(agg_u, cu, bp1, bl1, nu, NU);

    cu = nu;
    ci = ni;
  }
}